// Round 4
// baseline (248.036 us; speedup 1.0000x reference)
//
#include <hip/hip_runtime.h>

#define HH 256
#define WW 704
#define DD 64
#define CC 3
#define BB 2
#define HWN (HH * WW)       // 180224
#define TILE 16
#define TXT 44              // 704/16
#define TYT 16              // 256/16
#define Q0DIM 20            // tile + 2*2 halo (q0)
#define Q1DIM 18            // tile + 2*1 halo (q1)
#define P0W 66              // f32 words per px in q0 LDS (64 + 2 pad) -> bank stride 2
#define P1W 34              // dwords per px in q1 LDS (64 bf16 + 4 pad) -> bank stride 2

static constexpr float INV2Z2 = 1.0f / (2.0f * 1e-3f * 1e-3f);

// ---------------------------------------------------------------------------
// Affinity: kaff[b,k,n] = ws * exp(-sum_c (uc-c)^2/(2 zeta^2))
// ---------------------------------------------------------------------------
__global__ __launch_bounds__(256) void affinity_kernel(
    const float* __restrict__ color, const float* __restrict__ wsp,
    float* __restrict__ kaff)
{
    int n = blockIdx.x * 256 + threadIdx.x;
    int b = blockIdx.y;
    int h = n / WW, w = n - h * WW;
    float wsv = wsp[0];

    const float* cb = color + (size_t)b * CC * HWN + n;
    float c0 = cb[0], c1 = cb[HWN], c2 = cb[2 * HWN];
    bool hm = h > 0, hp = h < HH - 1, wm = w > 0, wp = w < WW - 1;

    float* kb = kaff + (size_t)b * 9 * HWN + n;
#pragma unroll
    for (int dh = -1; dh <= 1; ++dh) {
#pragma unroll
        for (int dw = -1; dw <= 1; ++dw) {
            int k = (dh + 1) * 3 + (dw + 1);
            bool valid = (dh < 0 ? hm : (dh > 0 ? hp : true)) &&
                         (dw < 0 ? wm : (dw > 0 ? wp : true));
            int off = valid ? (dh * WW + dw) : 0;
            float u0 = valid ? cb[off] : 0.f;
            float u1 = valid ? cb[HWN + off] : 0.f;
            float u2 = valid ? cb[2 * HWN + off] : 0.f;
            float d0 = u0 - c0, d1 = u1 - c1, d2 = u2 - c2;
            float ss = d0 * d0 + d1 * d1 + d2 * d2;
            kb[(size_t)k * HWN] = wsv * __expf(-ss * INV2Z2);
        }
    }
}

// bf16 helpers (RNE)
__device__ __forceinline__ unsigned pack_bf16(float a, float b) {
    unsigned ua = __float_as_uint(a), ub = __float_as_uint(b);
    ua = (ua + 0x7fffu + ((ua >> 16) & 1u)) >> 16;
    ub = (ub + 0x7fffu + ((ub >> 16) & 1u)) >> 16;
    return ua | (ub << 16);
}
__device__ __forceinline__ float blo(unsigned u) { return __uint_as_float(u << 16); }
__device__ __forceinline__ float bhi(unsigned u) { return __uint_as_float(u & 0xffff0000u); }

// 9-tap FMA on a bf16 pair lane (lo = even ch, hi = odd ch)
__device__ __forceinline__ void fma9_pair(
    unsigned u0, unsigned u1, unsigned u2, unsigned u3, unsigned u4,
    unsigned u5, unsigned u6, unsigned u7, unsigned u8,
    float k0, float k1, float k2, float k3, float k4,
    float k5, float k6, float k7, float k8, float& lo, float& hi)
{
    lo = k0 * blo(u0) + k1 * blo(u1) + k2 * blo(u2)
       + k3 * blo(u3) + k4 * blo(u4) + k5 * blo(u5)
       + k6 * blo(u6) + k7 * blo(u7) + k8 * blo(u8);
    hi = k0 * bhi(u0) + k1 * bhi(u1) + k2 * bhi(u2)
       + k3 * bhi(u3) + k4 * bhi(u4) + k5 * bhi(u5)
       + k6 * bhi(u6) + k7 * bhi(u7) + k8 * bhi(u8);
}

// ---------------------------------------------------------------------------
// Fused CRF: per 16x16 tile:
//   phase0: q0 = softmax(logits) on 20x20 (2-halo) -> LDS f32
//   phase1: q1 = CRF iter(q0)    on 18x18 (1-halo) -> LDS bf16
//   phase2: q2 = CRF iter(q1)    on 16x16          -> global
// Per px: 4 lanes x 16 ch (pxl = lane&15, cg = lane>>4); |d-e| matvec via
// prefix sums (A,Bp) with 4-way shfl scan; softmax w/o max-sub (|v|<=~15).
// Out-of-image halo px: addresses clamped (finite garbage), weights masked.
// ---------------------------------------------------------------------------
__global__ __launch_bounds__(1024) void fused_crf_kernel(
    const float* __restrict__ logits, const float* __restrict__ kaff,
    float* __restrict__ qout)
{
    __shared__ float q0s[Q0DIM * Q0DIM * P0W];      // 105,600 B
    __shared__ unsigned q1s[Q1DIM * Q1DIM * P1W];   //  44,064 B

    const int t = threadIdx.x;
    const int lane = t & 63;
    const int wv = t >> 6;            // 0..15
    const int pxl = lane & 15;
    const int cg = lane >> 4;         // ch block [16cg, 16cg+16)
    const int b = blockIdx.y;

    const int bid = blockIdx.x;       // 0..703, XCD swizzle (704%8==0, bijective)
    const int pb = (bid & 7) * (TYT * TXT / 8) + (bid >> 3);
    const int ty = pb / TXT, tx = pb - ty * TXT;
    const int y0 = ty * TILE, x0 = tx * TILE;

    const float* lgb = logits + ((size_t)b * DD + cg * 16) * HWN;
    const float* kfb = kaff + (size_t)b * 9 * HWN;

    // ---------------- phase 0: q0 = softmax(logits), 20x20 ----------------
#pragma unroll
    for (int r = 0; r < 2; ++r) {
        int p = r * 256 + wv * 16 + pxl;
        if (p < Q0DIM * Q0DIM) {
            int py = p / Q0DIM, px = p - py * Q0DIM;
            int gy = min(max(y0 - 2 + py, 0), HH - 1);
            int gx = min(max(x0 - 2 + px, 0), WW - 1);
            const float* lg = lgb + gy * WW + gx;
            float v[16];
            float s = 0.f;
#pragma unroll
            for (int i = 0; i < 16; ++i) {
                v[i] = __expf(lg[(size_t)i * HWN]);
                s += v[i];
            }
            s += __shfl_xor(s, 16);
            s += __shfl_xor(s, 32);
            float inv = 1.0f / s;
            float* q0p = q0s + p * P0W + cg * 16;
#pragma unroll
            for (int i = 0; i < 16; i += 4) {
                *(float4*)(q0p + i) =
                    make_float4(v[i] * inv, v[i+1] * inv, v[i+2] * inv, v[i+3] * inv);
            }
        }
    }
    __syncthreads();

    // ---------------- phase 1: q1 = iter(q0), 18x18, bf16 ----------------
#pragma unroll
    for (int r = 0; r < 2; ++r) {
        int p = r * 256 + wv * 16 + pxl;
        if (p < Q1DIM * Q1DIM) {
            int py = p / Q1DIM, px = p - py * Q1DIM;
            int gy = y0 - 1 + py, gx = x0 - 1 + px;           // may be out of image
            int cy = min(max(gy, 0), HH - 1), cx = min(max(gx, 0), WW - 1);
            int n = cy * WW + cx;

            float k0 = kfb[0 * HWN + n], k1 = kfb[1 * HWN + n], k2 = kfb[2 * HWN + n];
            float k3 = kfb[3 * HWN + n], k4 = kfb[4 * HWN + n], k5 = kfb[5 * HWN + n];
            float k6 = kfb[6 * HWN + n], k7 = kfb[7 * HWN + n], k8 = kfb[8 * HWN + n];
            if (gy <= 0)      { k0 = k1 = k2 = 0.f; }
            if (gy >= HH - 1) { k6 = k7 = k8 = 0.f; }
            if (gx <= 0)      { k0 = k3 = k6 = 0.f; }
            if (gx >= WW - 1) { k2 = k5 = k8 = 0.f; }

            const float* q00 = q0s + (py * Q0DIM + px) * P0W + cg * 16;
            float tv[16];
            float Aloc = 0.f, Bloc = 0.f;
#pragma unroll
            for (int i = 0; i < 4; ++i) {
                const float* qb = q00 + i * 4;
                float4 a0 = *(const float4*)(qb + 0 * P0W);
                float4 a1 = *(const float4*)(qb + 1 * P0W);
                float4 a2 = *(const float4*)(qb + 2 * P0W);
                float4 a3 = *(const float4*)(qb + (Q0DIM + 0) * P0W);
                float4 a4 = *(const float4*)(qb + (Q0DIM + 1) * P0W);
                float4 a5 = *(const float4*)(qb + (Q0DIM + 2) * P0W);
                float4 a6 = *(const float4*)(qb + (2 * Q0DIM + 0) * P0W);
                float4 a7 = *(const float4*)(qb + (2 * Q0DIM + 1) * P0W);
                float4 a8 = *(const float4*)(qb + (2 * Q0DIM + 2) * P0W);
                float4 tt;
                tt.x = k0*a0.x + k1*a1.x + k2*a2.x + k3*a3.x + k4*a4.x
                     + k5*a5.x + k6*a6.x + k7*a7.x + k8*a8.x;
                tt.y = k0*a0.y + k1*a1.y + k2*a2.y + k3*a3.y + k4*a4.y
                     + k5*a5.y + k6*a6.y + k7*a7.y + k8*a8.y;
                tt.z = k0*a0.z + k1*a1.z + k2*a2.z + k3*a3.z + k4*a4.z
                     + k5*a5.z + k6*a6.z + k7*a7.z + k8*a8.z;
                tt.w = k0*a0.w + k1*a1.w + k2*a2.w + k3*a3.w + k4*a4.w
                     + k5*a5.w + k6*a6.w + k7*a7.w + k8*a8.w;
                float e0 = (float)(cg * 16 + i * 4);
                Aloc += tt.x + tt.y + tt.z + tt.w;
                Bloc += e0*tt.x + (e0+1.f)*tt.y + (e0+2.f)*tt.z + (e0+3.f)*tt.w;
                tv[i*4+0] = tt.x; tv[i*4+1] = tt.y; tv[i*4+2] = tt.z; tv[i*4+3] = tt.w;
            }

            // 4-way scan over cg
            float A0 = __shfl(Aloc, pxl),      A1 = __shfl(Aloc, pxl + 16),
                  A2 = __shfl(Aloc, pxl + 32), A3 = __shfl(Aloc, pxl + 48);
            float B0 = __shfl(Bloc, pxl),      B1 = __shfl(Bloc, pxl + 16),
                  B2 = __shfl(Bloc, pxl + 32), B3 = __shfl(Bloc, pxl + 48);
            float T = A0 + A1 + A2 + A3, E = B0 + B1 + B2 + B3;
            float Ar = 0.f, Br = 0.f;
            if (cg > 0) { Ar += A0; Br += B0; }
            if (cg > 1) { Ar += A1; Br += B1; }
            if (cg > 2) { Ar += A2; Br += B2; }

            const float* lg = lgb + n;
            float s = 0.f;
#pragma unroll
            for (int i = 0; i < 16; ++i) {
                float e = (float)(cg * 16 + i);
                Ar += tv[i]; Br += e * tv[i];
                float v = lg[(size_t)i * HWN] - (2.f * (e * Ar - Br) + E - e * T);
                tv[i] = __expf(v);
                s += tv[i];
            }
            s += __shfl_xor(s, 16);
            s += __shfl_xor(s, 32);
            float inv = 1.0f / s;

            unsigned* qp = q1s + p * P1W + cg * 8;
            uint4 w0, w1;
            w0.x = pack_bf16(tv[0]*inv,  tv[1]*inv);
            w0.y = pack_bf16(tv[2]*inv,  tv[3]*inv);
            w0.z = pack_bf16(tv[4]*inv,  tv[5]*inv);
            w0.w = pack_bf16(tv[6]*inv,  tv[7]*inv);
            w1.x = pack_bf16(tv[8]*inv,  tv[9]*inv);
            w1.y = pack_bf16(tv[10]*inv, tv[11]*inv);
            w1.z = pack_bf16(tv[12]*inv, tv[13]*inv);
            w1.w = pack_bf16(tv[14]*inv, tv[15]*inv);
            *(uint4*)(qp) = w0;
            *(uint4*)(qp + 4) = w1;
        }
    }
    __syncthreads();

    // ---------------- phase 2: q2 = iter(q1) -> global, 16x16 ----------------
    {
        int p = wv * 16 + pxl;                       // 0..255, all valid
        int py = p >> 4, px = p & 15;
        int gy = y0 + py, gx = x0 + px;              // always in image
        int n = gy * WW + gx;

        float k0 = kfb[0 * HWN + n], k1 = kfb[1 * HWN + n], k2 = kfb[2 * HWN + n];
        float k3 = kfb[3 * HWN + n], k4 = kfb[4 * HWN + n], k5 = kfb[5 * HWN + n];
        float k6 = kfb[6 * HWN + n], k7 = kfb[7 * HWN + n], k8 = kfb[8 * HWN + n];
        if (gy == 0)      { k0 = k1 = k2 = 0.f; }
        if (gy == HH - 1) { k6 = k7 = k8 = 0.f; }
        if (gx == 0)      { k0 = k3 = k6 = 0.f; }
        if (gx == WW - 1) { k2 = k5 = k8 = 0.f; }

        const unsigned* q1b = q1s + (py * Q1DIM + px) * P1W + cg * 8;
        float tv[16];
        float Aloc = 0.f, Bloc = 0.f;
#pragma unroll
        for (int i2 = 0; i2 < 2; ++i2) {
            uint4 u0 = *(const uint4*)(q1b + (0) * P1W + i2 * 4);
            uint4 u1 = *(const uint4*)(q1b + (1) * P1W + i2 * 4);
            uint4 u2 = *(const uint4*)(q1b + (2) * P1W + i2 * 4);
            uint4 u3 = *(const uint4*)(q1b + (Q1DIM + 0) * P1W + i2 * 4);
            uint4 u4 = *(const uint4*)(q1b + (Q1DIM + 1) * P1W + i2 * 4);
            uint4 u5 = *(const uint4*)(q1b + (Q1DIM + 2) * P1W + i2 * 4);
            uint4 u6 = *(const uint4*)(q1b + (2 * Q1DIM + 0) * P1W + i2 * 4);
            uint4 u7 = *(const uint4*)(q1b + (2 * Q1DIM + 1) * P1W + i2 * 4);
            uint4 u8 = *(const uint4*)(q1b + (2 * Q1DIM + 2) * P1W + i2 * 4);
            float lo, hi;
            fma9_pair(u0.x,u1.x,u2.x,u3.x,u4.x,u5.x,u6.x,u7.x,u8.x,
                      k0,k1,k2,k3,k4,k5,k6,k7,k8, lo, hi);
            tv[i2*8+0] = lo; tv[i2*8+1] = hi;
            fma9_pair(u0.y,u1.y,u2.y,u3.y,u4.y,u5.y,u6.y,u7.y,u8.y,
                      k0,k1,k2,k3,k4,k5,k6,k7,k8, lo, hi);
            tv[i2*8+2] = lo; tv[i2*8+3] = hi;
            fma9_pair(u0.z,u1.z,u2.z,u3.z,u4.z,u5.z,u6.z,u7.z,u8.z,
                      k0,k1,k2,k3,k4,k5,k6,k7,k8, lo, hi);
            tv[i2*8+4] = lo; tv[i2*8+5] = hi;
            fma9_pair(u0.w,u1.w,u2.w,u3.w,u4.w,u5.w,u6.w,u7.w,u8.w,
                      k0,k1,k2,k3,k4,k5,k6,k7,k8, lo, hi);
            tv[i2*8+6] = lo; tv[i2*8+7] = hi;
        }
#pragma unroll
        for (int i = 0; i < 16; ++i) {
            float e = (float)(cg * 16 + i);
            Aloc += tv[i];
            Bloc += e * tv[i];
        }

        float A0 = __shfl(Aloc, pxl),      A1 = __shfl(Aloc, pxl + 16),
              A2 = __shfl(Aloc, pxl + 32), A3 = __shfl(Aloc, pxl + 48);
        float B0 = __shfl(Bloc, pxl),      B1 = __shfl(Bloc, pxl + 16),
              B2 = __shfl(Bloc, pxl + 32), B3 = __shfl(Bloc, pxl + 48);
        float T = A0 + A1 + A2 + A3, E = B0 + B1 + B2 + B3;
        float Ar = 0.f, Br = 0.f;
        if (cg > 0) { Ar += A0; Br += B0; }
        if (cg > 1) { Ar += A1; Br += B1; }
        if (cg > 2) { Ar += A2; Br += B2; }

        const float* lg = lgb + n;
        float s = 0.f;
#pragma unroll
        for (int i = 0; i < 16; ++i) {
            float e = (float)(cg * 16 + i);
            Ar += tv[i]; Br += e * tv[i];
            float v = lg[(size_t)i * HWN] - (2.f * (e * Ar - Br) + E - e * T);
            tv[i] = __expf(v);
            s += tv[i];
        }
        s += __shfl_xor(s, 16);
        s += __shfl_xor(s, 32);
        float inv = 1.0f / s;

        float* qo = qout + ((size_t)b * DD + cg * 16) * HWN + n;
#pragma unroll
        for (int i = 0; i < 16; ++i) qo[(size_t)i * HWN] = tv[i] * inv;
    }
}

// ---------------------------------------------------------------------------
extern "C" void kernel_launch(void* const* d_in, const int* in_sizes, int n_in,
                              void* d_out, int out_size, void* d_ws, size_t ws_size,
                              hipStream_t stream) {
    const float* color  = (const float*)d_in[0];
    // d_in[1] = feats: unused by the forward pass
    const float* logits = (const float*)d_in[2];
    const float* wsp    = (const float*)d_in[3];

    float* q_out = (float*)d_out;
    float* kaff  = (float*)d_ws;          // [B,9,HW] ~13 MB

    dim3 gridA(HWN / 256, BB);
    affinity_kernel<<<gridA, 256, 0, stream>>>(color, wsp, kaff);

    dim3 gridF(TYT * TXT, BB);            // 704 tiles x 2 batches
    fused_crf_kernel<<<gridF, 1024, 0, stream>>>(logits, kaff, q_out);
}

// Round 5
// 129.741 us; speedup vs baseline: 1.9118x; 1.9118x over previous
//
#include <hip/hip_runtime.h>

#define HH 256
#define WW 704
#define DD 64
#define CC 3
#define BB 2
#define HWN (HH * WW)       // 180224

#define TY 8                // out-tile rows
#define TX 16               // out-tile cols
#define RY0 12              // q0 region rows (tile + 2*2 halo)
#define RX0 20              // q0 region cols
#define NP0 (RY0 * RX0)     // 240
#define RY1 10              // q1 region rows (tile + 2*1 halo)
#define RX1 18              // q1 region cols
#define NP1 (RY1 * RX1)     // 180
#define NTX (WW / TX)       // 44
#define NTY (HH / TY)       // 32
#define NTILES (NTX * NTY)  // 1408 (divisible by 8 -> bijective XCD swizzle)

static constexpr float INV2Z2 = 1.0f / (2.0f * 1e-3f * 1e-3f);

// ---------------------------------------------------------------------------
// Affinity: kaff[b,k,n] = ws * exp(-sum_c (uc-c)^2/(2 zeta^2))
// ---------------------------------------------------------------------------
__global__ __launch_bounds__(256) void affinity_kernel(
    const float* __restrict__ color, const float* __restrict__ wsp,
    float* __restrict__ kaff)
{
    int n = blockIdx.x * 256 + threadIdx.x;
    int b = blockIdx.y;
    int h = n / WW, w = n - h * WW;
    float wsv = wsp[0];

    const float* cb = color + (size_t)b * CC * HWN + n;
    float c0 = cb[0], c1 = cb[HWN], c2 = cb[2 * HWN];
    bool hm = h > 0, hp = h < HH - 1, wm = w > 0, wp = w < WW - 1;

    float* kb = kaff + (size_t)b * 9 * HWN + n;
#pragma unroll
    for (int dh = -1; dh <= 1; ++dh) {
#pragma unroll
        for (int dw = -1; dw <= 1; ++dw) {
            int k = (dh + 1) * 3 + (dw + 1);
            bool valid = (dh < 0 ? hm : (dh > 0 ? hp : true)) &&
                         (dw < 0 ? wm : (dw > 0 ? wp : true));
            int off = valid ? (dh * WW + dw) : 0;
            float u0 = valid ? cb[off] : 0.f;
            float u1 = valid ? cb[HWN + off] : 0.f;
            float u2 = valid ? cb[2 * HWN + off] : 0.f;
            float d0 = u0 - c0, d1 = u1 - c1, d2 = u2 - c2;
            float ss = d0 * d0 + d1 * d1 + d2 * d2;
            kb[(size_t)k * HWN] = wsv * __expf(-ss * INV2Z2);
        }
    }
}

// ---------------------------------------------------------------------------
// bf16 helpers (RNE)
// ---------------------------------------------------------------------------
__device__ __forceinline__ unsigned pack_bf16(float a, float b) {
    unsigned ua = __float_as_uint(a), ub = __float_as_uint(b);
    ua = (ua + 0x7fffu + ((ua >> 16) & 1u)) >> 16;
    ub = (ub + 0x7fffu + ((ub >> 16) & 1u)) >> 16;
    return ua | (ub << 16);
}
__device__ __forceinline__ float blo(unsigned u) { return __uint_as_float(u << 16); }
__device__ __forceinline__ float bhi(unsigned u) { return __uint_as_float(u & 0xffff0000u); }

// LDS layout: px-major, 32 dwords (64 bf16 ch) per px; XOR swizzle on the
// dword index: dw(p,q) = p*32 + (q ^ ((p&7)<<2)).  For a wave where p is
// linear in pxl and q = cg*8 (+4), each 4-bank group is hit by exactly 8
// lanes at distinct rows = the b128 minimum -> conflict-free.
__device__ __forceinline__ void acc_tap(const unsigned* q, int p0, int cg,
                                        float kw, float* tv) {
    int sw = (p0 & 7) << 2;
    uint4 ua = *(const uint4*)&q[p0 * 32 + ((cg * 8) ^ sw)];
    uint4 ub = *(const uint4*)&q[p0 * 32 + ((cg * 8 + 4) ^ sw)];
    tv[0]  += kw * blo(ua.x); tv[1]  += kw * bhi(ua.x);
    tv[2]  += kw * blo(ua.y); tv[3]  += kw * bhi(ua.y);
    tv[4]  += kw * blo(ua.z); tv[5]  += kw * bhi(ua.z);
    tv[6]  += kw * blo(ua.w); tv[7]  += kw * bhi(ua.w);
    tv[8]  += kw * blo(ub.x); tv[9]  += kw * bhi(ub.x);
    tv[10] += kw * blo(ub.y); tv[11] += kw * bhi(ub.y);
    tv[12] += kw * blo(ub.z); tv[13] += kw * bhi(ub.z);
    tv[14] += kw * blo(ub.w); tv[15] += kw * bhi(ub.w);
}

__device__ __forceinline__ void st_px(unsigned* q, int p, int cg, const float* u) {
    int sw = (p & 7) << 2;
    uint4 a, bu;
    a.x  = pack_bf16(u[0],  u[1]);  a.y  = pack_bf16(u[2],  u[3]);
    a.z  = pack_bf16(u[4],  u[5]);  a.w  = pack_bf16(u[6],  u[7]);
    bu.x = pack_bf16(u[8],  u[9]);  bu.y = pack_bf16(u[10], u[11]);
    bu.z = pack_bf16(u[12], u[13]); bu.w = pack_bf16(u[14], u[15]);
    *(uint4*)&q[p * 32 + ((cg * 8) ^ sw)] = a;
    *(uint4*)&q[p * 32 + ((cg * 8 + 4) ^ sw)] = bu;
}

// 4-way exclusive prefix + totals over channel-groups (lanes pxl+16g all
// share the same task id -> divergence-safe inside partial rounds)
__device__ __forceinline__ void scan4(float Aloc, float Bloc, int pxl, int cg,
                                      float& Ar, float& Br, float& T, float& E) {
    float A0 = __shfl(Aloc, pxl),      A1 = __shfl(Aloc, pxl + 16),
          A2 = __shfl(Aloc, pxl + 32), A3 = __shfl(Aloc, pxl + 48);
    float B0 = __shfl(Bloc, pxl),      B1 = __shfl(Bloc, pxl + 16),
          B2 = __shfl(Bloc, pxl + 32), B3 = __shfl(Bloc, pxl + 48);
    T = A0 + A1 + A2 + A3;  E = B0 + B1 + B2 + B3;
    Ar = 0.f; Br = 0.f;
    if (cg > 0) { Ar += A0; Br += B0; }
    if (cg > 1) { Ar += A1; Br += B1; }
    if (cg > 2) { Ar += A2; Br += B2; }
}

// tv[i] = t[e] -> exp(logit - q_hat); returns 1/sum over all 64 ch
__device__ __forceinline__ float finish_px(float* tv, const float* lg,
                                           int pxl, int cg) {
    float Aloc = 0.f, Bloc = 0.f;
#pragma unroll
    for (int i = 0; i < 16; ++i) {
        float e = (float)(cg * 16 + i);
        Aloc += tv[i]; Bloc += e * tv[i];
    }
    float Ar, Br, T, E;
    scan4(Aloc, Bloc, pxl, cg, Ar, Br, T, E);
    float s = 0.f;
#pragma unroll
    for (int i = 0; i < 16; ++i) {
        float e = (float)(cg * 16 + i);
        Ar += tv[i]; Br += e * tv[i];
        float v = lg[(size_t)i * HWN] - (2.f * (e * Ar - Br) + E - e * T);
        tv[i] = __expf(v); s += tv[i];
    }
    s += __shfl_xor(s, 16);
    s += __shfl_xor(s, 32);
    return 1.f / s;
}

__device__ __forceinline__ void load_k(const float* kfb, int n, int gy, int gx,
                                       float* k) {
#pragma unroll
    for (int j = 0; j < 9; ++j) k[j] = kfb[(size_t)j * HWN + n];
    if (gy <= 0)      { k[0] = k[1] = k[2] = 0.f; }
    if (gy >= HH - 1) { k[6] = k[7] = k[8] = 0.f; }
    if (gx <= 0)      { k[0] = k[3] = k[6] = 0.f; }
    if (gx >= WW - 1) { k[2] = k[5] = k[8] = 0.f; }
}

// ---------------------------------------------------------------------------
// Fused CRF per 8x16 out-tile:
//   P0: q0 = softmax(logits) on 12x20 (coords clamped -> real values) -> LDS bf16
//   P1: q1 = iter(q0) on 10x18 -> LDS bf16 (out-of-image px garbage-but-finite,
//       masked downstream)
//   P2: q2 = iter(q1) on 8x16 -> global
// Task = 1 px, 4 lanes x 16 ch (pxl = lane&15, cg = lane>>4); 64 tasks/round.
// ---------------------------------------------------------------------------
__global__ __launch_bounds__(256) void fused_crf_kernel(
    const float* __restrict__ logits, const float* __restrict__ kaff,
    float* __restrict__ qout)
{
    __shared__ unsigned q0s[NP0 * 32];   // 30,720 B
    __shared__ unsigned q1s[NP1 * 32];   // 23,040 B

    const int t = threadIdx.x;
    const int lane = t & 63;
    const int wv = t >> 6;          // 0..3
    const int pxl = lane & 15;
    const int cg = lane >> 4;       // channels [16cg, 16cg+16)
    const int b = blockIdx.y;

    const int bid = blockIdx.x;     // XCD swizzle (1408 % 8 == 0 -> bijective)
    const int pb = (bid & 7) * (NTILES / 8) + (bid >> 3);
    const int tyr = pb / NTX, txc = pb - tyr * NTX;
    const int y0 = tyr * TY, x0 = txc * TX;

    const float* lgb = logits + ((size_t)b * DD + cg * 16) * HWN;
    const float* kfb = kaff + (size_t)b * 9 * HWN;

    // ---------------- P0: q0 = softmax(logits) on 12x20 ----------------
    for (int r = 0; r < 4; ++r) {
        int id = r * 64 + wv * 16 + pxl;
        if (id < NP0) {
            int py = id / RX0, px = id - py * RX0;
            int gy = min(max(y0 - 2 + py, 0), HH - 1);
            int gx = min(max(x0 - 2 + px, 0), WW - 1);
            const float* lg = lgb + gy * WW + gx;
            float v[16];
            float s = 0.f;
#pragma unroll
            for (int i = 0; i < 16; ++i) {
                v[i] = __expf(lg[(size_t)i * HWN]);
                s += v[i];
            }
            s += __shfl_xor(s, 16);
            s += __shfl_xor(s, 32);
            float inv = 1.0f / s;
#pragma unroll
            for (int i = 0; i < 16; ++i) v[i] *= inv;
            st_px(q0s, id, cg, v);
        }
    }
    __syncthreads();

    // ---------------- P1: q1 = iter(q0) on 10x18 ----------------
    for (int r = 0; r < 3; ++r) {
        int id = r * 64 + wv * 16 + pxl;
        if (id < NP1) {
            int py = id / RX1, px = id - py * RX1;
            int gy = y0 - 1 + py, gx = x0 - 1 + px;   // may be out of image
            int cy = min(max(gy, 0), HH - 1), cx = min(max(gx, 0), WW - 1);
            int n = cy * WW + cx;

            float k[9];
            load_k(kfb, n, gy, gx, k);

            float tv[16];
#pragma unroll
            for (int i = 0; i < 16; ++i) tv[i] = 0.f;
#pragma unroll
            for (int tap = 0; tap < 9; ++tap) {
                int dy = tap / 3 - 1, dx = tap - (tap / 3) * 3 - 1;
                int p0 = (py + 1 + dy) * RX0 + (px + 1 + dx);
                acc_tap(q0s, p0, cg, k[tap], tv);
            }
            float inv = finish_px(tv, lgb + n, pxl, cg);
#pragma unroll
            for (int i = 0; i < 16; ++i) tv[i] *= inv;
            st_px(q1s, id, cg, tv);
        }
    }
    __syncthreads();

    // ---------------- P2: q2 = iter(q1) -> global, 8x16 ----------------
    for (int r = 0; r < 2; ++r) {
        int id = r * 64 + wv * 16 + pxl;     // 0..127, all valid
        int py = id / TX, px = id - py * TX;
        int gy = y0 + py, gx = x0 + px;      // always in image
        int n = gy * WW + gx;

        float k[9];
        load_k(kfb, n, gy, gx, k);

        float tv[16];
#pragma unroll
        for (int i = 0; i < 16; ++i) tv[i] = 0.f;
#pragma unroll
        for (int tap = 0; tap < 9; ++tap) {
            int dy = tap / 3 - 1, dx = tap - (tap / 3) * 3 - 1;
            int p1 = (py + 1 + dy) * RX1 + (px + 1 + dx);
            acc_tap(q1s, p1, cg, k[tap], tv);
        }
        float inv = finish_px(tv, lgb + n, pxl, cg);

        float* qo = qout + ((size_t)b * DD + cg * 16) * HWN + n;
#pragma unroll
        for (int i = 0; i < 16; ++i) qo[(size_t)i * HWN] = tv[i] * inv;
    }
}

// ---------------------------------------------------------------------------
extern "C" void kernel_launch(void* const* d_in, const int* in_sizes, int n_in,
                              void* d_out, int out_size, void* d_ws, size_t ws_size,
                              hipStream_t stream) {
    const float* color  = (const float*)d_in[0];
    // d_in[1] = feats: unused by the forward pass
    const float* logits = (const float*)d_in[2];
    const float* wsp    = (const float*)d_in[3];

    float* q_out = (float*)d_out;
    float* kaff  = (float*)d_ws;          // [B,9,HW] ~13 MB

    dim3 gridA(HWN / 256, BB);
    affinity_kernel<<<gridA, 256, 0, stream>>>(color, wsp, kaff);

    dim3 gridF(NTILES, BB);               // 1408 tiles x 2 batches
    fused_crf_kernel<<<gridF, 256, 0, stream>>>(logits, kaff, q_out);
}

// Round 6
// 98.623 us; speedup vs baseline: 2.5150x; 1.3155x over previous
//
#include <hip/hip_runtime.h>
#include <hip/hip_fp16.h>

#define HH 256
#define WW 704
#define DD 64
#define CC 3
#define BB 2
#define HWN (HH * WW)       // 180224

#define TY 8                // out-tile rows
#define TX 16               // out-tile cols
#define RY0 12              // q0 region rows (tile + 2*2 halo)
#define RX0 20              // q0 region cols
#define NP0 (RY0 * RX0)     // 240
#define RY1 10              // q1 region rows (tile + 2*1 halo)
#define RX1 18              // q1 region cols
#define NP1 (RY1 * RX1)     // 180
#define NTX (WW / TX)       // 44
#define NTY (HH / TY)       // 32
#define NTILES (NTX * NTY)  // 1408 (divisible by 8 -> bijective XCD swizzle)

static constexpr float INV2Z2 = 1.0f / (2.0f * 1e-3f * 1e-3f);

// ---------------------------------------------------------------------------
// Affinity: kaff[b,k,n] = ws * exp(-sum_c (uc-c)^2/(2 zeta^2))
// ---------------------------------------------------------------------------
__global__ __launch_bounds__(256) void affinity_kernel(
    const float* __restrict__ color, const float* __restrict__ wsp,
    float* __restrict__ kaff)
{
    int n = blockIdx.x * 256 + threadIdx.x;
    int b = blockIdx.y;
    int h = n / WW, w = n - h * WW;
    float wsv = wsp[0];

    const float* cb = color + (size_t)b * CC * HWN + n;
    float c0 = cb[0], c1 = cb[HWN], c2 = cb[2 * HWN];
    bool hm = h > 0, hp = h < HH - 1, wm = w > 0, wp = w < WW - 1;

    float* kb = kaff + (size_t)b * 9 * HWN + n;
#pragma unroll
    for (int dh = -1; dh <= 1; ++dh) {
#pragma unroll
        for (int dw = -1; dw <= 1; ++dw) {
            int k = (dh + 1) * 3 + (dw + 1);
            bool valid = (dh < 0 ? hm : (dh > 0 ? hp : true)) &&
                         (dw < 0 ? wm : (dw > 0 ? wp : true));
            int off = valid ? (dh * WW + dw) : 0;
            float u0 = valid ? cb[off] : 0.f;
            float u1 = valid ? cb[HWN + off] : 0.f;
            float u2 = valid ? cb[2 * HWN + off] : 0.f;
            float d0 = u0 - c0, d1 = u1 - c1, d2 = u2 - c2;
            float ss = d0 * d0 + d1 * d1 + d2 * d2;
            kb[(size_t)k * HWN] = wsv * __expf(-ss * INV2Z2);
        }
    }
}

// ---------------------------------------------------------------------------
// LDS layout: px-major, 32 dwords (64 f16 ch) per px, XOR swizzle on the
// dword index: dw(p, q) = p*32 + (q ^ ((p&7)<<2)).  Swizzle bits (2..4)
// don't overlap the in-group bits (0..1), so a logical aligned 4-dword
// group stays a physical aligned 4-dword group, and the group at logical
// +4 sits at physical (addr ^ 4 dwords) -> one addr calc + XOR.
// Store/load use the same permutation -> correctness independent of mixing.
// ---------------------------------------------------------------------------
__device__ __forceinline__ void acc_tap(const unsigned* q, int p0, int cg,
                                        __half2 kh, __half2* tv2) {
    int ia = p0 * 32 + ((cg * 8) ^ ((p0 & 7) << 2));
    int ib = ia ^ 4;
    const __half2* qa = (const __half2*)&q[ia];  // ch 16cg+0..7  (pairs)
    const __half2* qb = (const __half2*)&q[ib];  // ch 16cg+8..15 (pairs)
    tv2[0] = __hfma2(kh, qa[0], tv2[0]);
    tv2[1] = __hfma2(kh, qa[1], tv2[1]);
    tv2[2] = __hfma2(kh, qa[2], tv2[2]);
    tv2[3] = __hfma2(kh, qa[3], tv2[3]);
    tv2[4] = __hfma2(kh, qb[0], tv2[4]);
    tv2[5] = __hfma2(kh, qb[1], tv2[5]);
    tv2[6] = __hfma2(kh, qb[2], tv2[6]);
    tv2[7] = __hfma2(kh, qb[3], tv2[7]);
}

// store 16 channels (u[i]*scale) as f16 pairs
__device__ __forceinline__ void st_px(unsigned* q, int p, int cg,
                                      const float* u, float scale) {
    int ia = p * 32 + ((cg * 8) ^ ((p & 7) << 2));
    int ib = ia ^ 4;
    __half2* qa = (__half2*)&q[ia];
    __half2* qb = (__half2*)&q[ib];
    qa[0] = __floats2half2_rn(u[0]  * scale, u[1]  * scale);
    qa[1] = __floats2half2_rn(u[2]  * scale, u[3]  * scale);
    qa[2] = __floats2half2_rn(u[4]  * scale, u[5]  * scale);
    qa[3] = __floats2half2_rn(u[6]  * scale, u[7]  * scale);
    qb[0] = __floats2half2_rn(u[8]  * scale, u[9]  * scale);
    qb[1] = __floats2half2_rn(u[10] * scale, u[11] * scale);
    qb[2] = __floats2half2_rn(u[12] * scale, u[13] * scale);
    qb[3] = __floats2half2_rn(u[14] * scale, u[15] * scale);
}

// 4-way exclusive prefix + totals over channel-groups (shfl partners at
// pxl+16g share the same task id -> divergence-safe in partial rounds)
__device__ __forceinline__ void scan4(float Aloc, float Bloc, int pxl, int cg,
                                      float& Ar, float& Br, float& T, float& E) {
    float A0 = __shfl(Aloc, pxl),      A1 = __shfl(Aloc, pxl + 16),
          A2 = __shfl(Aloc, pxl + 32), A3 = __shfl(Aloc, pxl + 48);
    float B0 = __shfl(Bloc, pxl),      B1 = __shfl(Bloc, pxl + 16),
          B2 = __shfl(Bloc, pxl + 32), B3 = __shfl(Bloc, pxl + 48);
    T = A0 + A1 + A2 + A3;  E = B0 + B1 + B2 + B3;
    Ar = 0.f; Br = 0.f;
    if (cg > 0) { Ar += A0; Br += B0; }
    if (cg > 1) { Ar += A1; Br += B1; }
    if (cg > 2) { Ar += A2; Br += B2; }
}

// tv[i] = t[e] -> exp(logit - q_hat); returns 1/sum over all 64 ch
__device__ __forceinline__ float finish_px(float* tv, const float* lg,
                                           int pxl, int cg) {
    float Aloc = 0.f, Bloc = 0.f;
#pragma unroll
    for (int i = 0; i < 16; ++i) {
        float e = (float)(cg * 16 + i);
        Aloc += tv[i]; Bloc += e * tv[i];
    }
    float Ar, Br, T, E;
    scan4(Aloc, Bloc, pxl, cg, Ar, Br, T, E);
    float s = 0.f;
#pragma unroll
    for (int i = 0; i < 16; ++i) {
        float e = (float)(cg * 16 + i);
        Ar += tv[i]; Br += e * tv[i];
        float v = lg[(size_t)i * HWN] - (2.f * (e * Ar - Br) + E - e * T);
        tv[i] = __expf(v); s += tv[i];
    }
    s += __shfl_xor(s, 16);
    s += __shfl_xor(s, 32);
    return 1.f / s;
}

__device__ __forceinline__ void load_k(const float* kfb, int n, int gy, int gx,
                                       float* k) {
#pragma unroll
    for (int j = 0; j < 9; ++j) k[j] = kfb[(size_t)j * HWN + n];
    if (gy <= 0)      { k[0] = k[1] = k[2] = 0.f; }
    if (gy >= HH - 1) { k[6] = k[7] = k[8] = 0.f; }
    if (gx <= 0)      { k[0] = k[3] = k[6] = 0.f; }
    if (gx >= WW - 1) { k[2] = k[5] = k[8] = 0.f; }
}

// 9-tap stencil from an LDS q-region into tv[16] (f32), via packed f16 FMA
__device__ __forceinline__ void stencil9(const unsigned* qs, int rowstride,
                                         int py, int px, int cg,
                                         const float* k, float* tv) {
    __half2 tv2[8];
#pragma unroll
    for (int j = 0; j < 8; ++j) tv2[j] = __float2half2_rn(0.f);
    int base = (py + 1) * rowstride + (px + 1);
#pragma unroll
    for (int tap = 0; tap < 9; ++tap) {
        int dy = tap / 3 - 1, dx = tap - (tap / 3) * 3 - 1;
        acc_tap(qs, base + dy * rowstride + dx, cg, __float2half2_rn(k[tap]), tv2);
    }
#pragma unroll
    for (int j = 0; j < 8; ++j) {
        float2 f = __half22float2(tv2[j]);
        tv[2 * j] = f.x; tv[2 * j + 1] = f.y;
    }
}

// ---------------------------------------------------------------------------
// Fused CRF per 8x16 out-tile:
//   P0: q0 = softmax(logits) on 12x20 (clamped coords) -> LDS f16
//   P1: q1 = iter(q0) on 10x18 -> LDS f16 (out-of-image px: clamped-coord
//       values, bounded in [0,1], masked by weights downstream)
//   P2: q2 = iter(q1) on 8x16 -> global
// Task = 1 px, 4 lanes x 16 ch (pxl = lane&15, cg = lane>>4); 64 tasks/round.
// ---------------------------------------------------------------------------
__global__ __launch_bounds__(256) void fused_crf_kernel(
    const float* __restrict__ logits, const float* __restrict__ kaff,
    float* __restrict__ qout)
{
    __shared__ unsigned q0s[NP0 * 32];   // 30,720 B
    __shared__ unsigned q1s[NP1 * 32];   // 23,040 B

    const int t = threadIdx.x;
    const int lane = t & 63;
    const int wv = t >> 6;          // 0..3
    const int pxl = lane & 15;
    const int cg = lane >> 4;       // channels [16cg, 16cg+16)
    const int b = blockIdx.y;

    const int bid = blockIdx.x;     // XCD swizzle (1408 % 8 == 0 -> bijective)
    const int pb = (bid & 7) * (NTILES / 8) + (bid >> 3);
    const int tyr = pb / NTX, txc = pb - tyr * NTX;
    const int y0 = tyr * TY, x0 = txc * TX;

    const float* lgb = logits + ((size_t)b * DD + cg * 16) * HWN;
    const float* kfb = kaff + (size_t)b * 9 * HWN;

    // ---------------- P0: q0 = softmax(logits) on 12x20 ----------------
    for (int r = 0; r < 4; ++r) {
        int id = r * 64 + wv * 16 + pxl;
        if (id < NP0) {
            int py = id / RX0, px = id - py * RX0;
            int gy = min(max(y0 - 2 + py, 0), HH - 1);
            int gx = min(max(x0 - 2 + px, 0), WW - 1);
            const float* lg = lgb + gy * WW + gx;
            float v[16];
            float s = 0.f;
#pragma unroll
            for (int i = 0; i < 16; ++i) {
                v[i] = __expf(lg[(size_t)i * HWN]);
                s += v[i];
            }
            s += __shfl_xor(s, 16);
            s += __shfl_xor(s, 32);
            st_px(q0s, id, cg, v, 1.0f / s);
        }
    }
    __syncthreads();

    // ---------------- P1: q1 = iter(q0) on 10x18 ----------------
    for (int r = 0; r < 3; ++r) {
        int id = r * 64 + wv * 16 + pxl;
        if (id < NP1) {
            int py = id / RX1, px = id - py * RX1;
            int gy = y0 - 1 + py, gx = x0 - 1 + px;   // may be out of image
            int cy = min(max(gy, 0), HH - 1), cx = min(max(gx, 0), WW - 1);
            int n = cy * WW + cx;

            float k[9];
            load_k(kfb, n, gy, gx, k);

            float tv[16];
            stencil9(q0s, RX0, py, px, cg, k, tv);
            float inv = finish_px(tv, lgb + n, pxl, cg);
            st_px(q1s, id, cg, tv, inv);
        }
    }
    __syncthreads();

    // ---------------- P2: q2 = iter(q1) -> global, 8x16 ----------------
    for (int r = 0; r < 2; ++r) {
        int id = r * 64 + wv * 16 + pxl;     // 0..127, all valid
        int py = id / TX, px = id - py * TX;
        int gy = y0 + py, gx = x0 + px;      // always in image
        int n = gy * WW + gx;

        float k[9];
        load_k(kfb, n, gy, gx, k);

        float tv[16];
        stencil9(q1s, RX1, py, px, cg, k, tv);
        float inv = finish_px(tv, lgb + n, pxl, cg);

        float* qo = qout + ((size_t)b * DD + cg * 16) * HWN + n;
#pragma unroll
        for (int i = 0; i < 16; ++i) qo[(size_t)i * HWN] = tv[i] * inv;
    }
}

// ---------------------------------------------------------------------------
extern "C" void kernel_launch(void* const* d_in, const int* in_sizes, int n_in,
                              void* d_out, int out_size, void* d_ws, size_t ws_size,
                              hipStream_t stream) {
    const float* color  = (const float*)d_in[0];
    // d_in[1] = feats: unused by the forward pass
    const float* logits = (const float*)d_in[2];
    const float* wsp    = (const float*)d_in[3];

    float* q_out = (float*)d_out;
    float* kaff  = (float*)d_ws;          // [B,9,HW] ~13 MB

    dim3 gridA(HWN / 256, BB);
    affinity_kernel<<<gridA, 256, 0, stream>>>(color, wsp, kaff);

    dim3 gridF(NTILES, BB);               // 1408 tiles x 2 batches
    fused_crf_kernel<<<gridF, 256, 0, stream>>>(logits, kaff, q_out);
}